// Round 3
// baseline (85.959 us; speedup 1.0000x reference)
//
#include <hip/hip_runtime.h>
#include <math.h>

#define Bn   512
#define Tn   50
#define NAn  5
#define NCn  7
#define GHn  16
#define GWn  32
#define CELLS (NAn*GHn*GWn)       // 2560 cells per batch
#define SBLK  640                 // streaming blocks: 640*256*2 float4 = all conf
#define NF4   (Bn*NAn*128)        // total float4 in conf planes = 327680
#define TOTAL_CELLS (Bn*CELLS)    // 1310720
#define NBLK  (SBLK + Bn)
#define EXCL  0x8000

__device__ __constant__ float c_aw[NAn] = {1.0f, 2.0f, 3.5f, 5.0f, 8.0f};
__device__ __constant__ float c_ah[NAn] = {1.5f, 3.0f, 4.5f, 6.0f, 10.0f};

__device__ inline float sigm(float v) { return 1.0f / (1.0f + expf(-v)); }
// -log(clip(1 - sigmoid(v), 1e-12)) — bit-identical in stream & correction
__device__ inline float negterm(float v) {
  return -logf(fmaxf(1.0f - sigm(v), 1e-12f));
}

__device__ inline float wred(float v) {
#pragma unroll
  for (int off = 32; off > 0; off >>= 1) v += __shfl_down(v, off, 64);
  return v;
}

// ws layout: float acc[6]  (mse, pos_conf, cls, neg_sum, n_pos, neg_corr)
//            int   ticket  at ((int*)ws)[7]
__global__ __launch_bounds__(256) void k_fused(const float* __restrict__ x,
                                               const float* __restrict__ tg,
                                               float* __restrict__ ws,
                                               float* __restrict__ out)
{
  const int tid = threadIdx.x;
  float v_mse = 0.f, v_pc = 0.f, v_cls = 0.f, v_neg = 0.f, v_np = 0.f, v_nc = 0.f;

  if (blockIdx.x < SBLK) {
    // ---------- streaming role: full neg-BCE sum over ALL conf cells ----------
    const int gid = blockIdx.x * 256 + tid;
#pragma unroll
    for (int k = 0; k < 2; ++k) {
      int idx = gid + k * (SBLK * 256);          // < NF4 always
      int plane = idx >> 7;                      // 128 float4 per plane
      int rest  = idx & 127;
      int b = plane / NAn;
      int a = plane - b * NAn;
      size_t off = (((size_t)b * (NAn * 14) + a * 14 + 6) * 512) + rest * 4;
      const float4 v = *reinterpret_cast<const float4*>(x + off);
      v_neg += negterm(v.x) + negterm(v.y) + negterm(v.z) + negterm(v.w);
    }
  } else {
    // ---------- target role: one block per batch, cell-parallel ----------
    const int b = blockIdx.x - SBLK;

    __shared__ int   s_owner[CELLS];   // last-wins winner tid per cell, -1 none
    __shared__ int   s_flags[CELLS];   // bits 0..6: label set; bit15: mask|ignore
    __shared__ float s_tx[Tn], s_ty[Tn], s_tw[Tn], s_th[Tn];

    for (int i = tid; i < CELLS; i += 256) { s_owner[i] = -1; s_flags[i] = 0; }
    __syncthreads();

    if (tid < Tn) {
      const float* tp = tg + ((size_t)b * Tn + tid) * 5;
      float c0 = tp[0], c1 = tp[1], c2 = tp[2], c3 = tp[3], c4 = tp[4];
      bool valid = (c0 + c1 + c2 + c3 + c4) > 0.0f;
      float gx = c1 * (float)GWn, gy = c2 * (float)GHn;
      float gw = c3 * (float)GWn, gh = c4 * (float)GHn;
      float iou[NAn];
      int best = 0; float bestv = -1.0f;
#pragma unroll
      for (int a = 0; a < NAn; ++a) {
        float inter = fminf(gw, c_aw[a]) * fminf(gh, c_ah[a]);
        float u = inter / (gw * gh + c_aw[a] * c_ah[a] - inter + 1e-16f);
        iou[a] = u;
        if (u > bestv) { bestv = u; best = a; }   // first-max like argmax
      }
      int gi = (int)floorf(gx), gj = (int)floorf(gy);
      bool inb = (gi >= 0) && (gi < GWn) && (gj >= 0) && (gj < GHn); // mode='drop'
      s_tx[tid] = gx - floorf(gx);
      s_ty[tid] = gy - floorf(gy);
      s_tw[tid] = logf(gw / c_aw[best] + 1e-16f);
      s_th[tid] = logf(gh / c_ah[best] + 1e-16f);
      if (valid && inb) {
        int cell = best * (GHn * GWn) + gj * GWn + gi;
        atomicMax(&s_owner[cell], tid);           // last-wins = max tid
        int lbl = (int)c0;                        // astype(int32)
        int lb  = (lbl >= 0 && lbl < NCn) ? (1 << lbl) : 0;  // mode='drop'
        atomicOr(&s_flags[cell], lb | EXCL);
#pragma unroll
        for (int a = 0; a < NAn; ++a) if (iou[a] > 0.6f)
          atomicOr(&s_flags[a * (GHn * GWn) + gj * GWn + gi], EXCL);
      }
    }
    __syncthreads();

    const float* xb = x + (size_t)b * (NAn * 14) * 512;
#pragma unroll
    for (int it = 0; it < CELLS / 256; ++it) {
      int cell  = tid + it * 256;
      int flags = s_flags[cell];
      if (flags) {
        int owner = s_owner[cell];
        int a = cell >> 9, rest = cell & 511;
        const float* pl = xb + a * 14 * 512;
        float p6 = pl[6 * 512 + rest];
        // correction: cancel this cell out of the streaming full-sum
        v_neg -= negterm(p6);
        v_nc  -= 1.0f;
        if (owner >= 0) {                         // masked (positive) cell
          float p0 = pl[0 * 512 + rest];
          float p1 = pl[1 * 512 + rest];
          float p2 = pl[2 * 512 + rest];
          float p3 = pl[3 * 512 + rest];
          float dx = sigm(p0) - s_tx[owner];
          float dy = sigm(p1) - s_ty[owner];
          float dw = p2 - s_tw[owner];
          float dh = p3 - s_th[owner];
          v_mse += dx * dx + dy * dy + dw * dw + dh * dh;
          v_pc  += -logf(fmaxf(sigm(p6), 1e-12f));
          v_np  += 1.0f;
          int bits = flags & 0x7F;
          if (bits) {
            float s[NCn]; float m = -1e30f;
#pragma unroll
            for (int k = 0; k < NCn; ++k) {
              s[k] = sigm(pl[(size_t)(7 + k) * 512 + rest]);
              m = fmaxf(m, s[k]);
            }
            float ssum = 0.f;
#pragma unroll
            for (int k = 0; k < NCn; ++k) ssum += expf(s[k] - m);
            float lse = m + logf(ssum);
#pragma unroll
            for (int k = 0; k < NCn; ++k)
              if ((bits >> k) & 1) v_cls += lse - s[k];
          }
        }
      }
    }
  }

  // ---- block reduction (6 values) + global accumulate ----
  __shared__ float red6[4][6];
  float vals[6] = {v_mse, v_pc, v_cls, v_neg, v_np, v_nc};
  int wid = tid >> 6, lane = tid & 63;
#pragma unroll
  for (int k = 0; k < 6; ++k) {
    float r = wred(vals[k]);
    if (lane == 0) red6[wid][k] = r;
  }
  __syncthreads();
  if (tid == 0) {
#pragma unroll
    for (int k = 0; k < 6; ++k) {
      float s = red6[0][k] + red6[1][k] + red6[2][k] + red6[3][k];
      if (s != 0.0f) atomicAdd(&ws[k], s);
    }
    __threadfence();
    int old = atomicAdd((int*)ws + 7, 1);
    if (old == NBLK - 1) {                        // last block finalizes
      __threadfence();
      float a0 = atomicAdd(&ws[0], 0.0f);
      float a1 = atomicAdd(&ws[1], 0.0f);
      float a2 = atomicAdd(&ws[2], 0.0f);
      float a3 = atomicAdd(&ws[3], 0.0f);
      float a4 = atomicAdd(&ws[4], 0.0f);
      float a5 = atomicAdd(&ws[5], 0.0f);
      float npos = fmaxf(a4, 1.0f);
      float negc = fmaxf((float)TOTAL_CELLS + a5, 1.0f);
      out[0] = a0 / npos + a3 / negc + a1 / npos + a2 / ((float)Bn * npos);
    }
  }
}

extern "C" void kernel_launch(void* const* d_in, const int* in_sizes, int n_in,
                              void* d_out, int out_size, void* d_ws, size_t ws_size,
                              hipStream_t stream)
{
  const float* x  = (const float*)d_in[0];
  const float* tg = (const float*)d_in[1];

  hipMemsetAsync(d_ws, 0, 8 * sizeof(float), stream);
  k_fused<<<NBLK, 256, 0, stream>>>(x, tg, (float*)d_ws, (float*)d_out);
}

// Round 4
// 29.845 us; speedup vs baseline: 2.8802x; 2.8802x over previous
//
#include <hip/hip_runtime.h>
#include <math.h>

#define Bn   512
#define Tn   50
#define NAn  5
#define NCn  7
#define GHn  16
#define GWn  32
#define CELLS (NAn*GHn*GWn)       // 2560 cells per batch
#define EXCL  0x8000

__device__ __constant__ float c_aw[NAn] = {1.0f, 2.0f, 3.5f, 5.0f, 8.0f};
__device__ __constant__ float c_ah[NAn] = {1.5f, 3.0f, 4.5f, 6.0f, 10.0f};

__device__ inline float sigm(float v) { return 1.0f / (1.0f + expf(-v)); }
__device__ inline float negterm(float v) {          // -log(clip(1-sigmoid(v)))
  return -logf(fmaxf(1.0f - sigm(v), 1e-12f));
}

__device__ inline float wred(float v) {
#pragma unroll
  for (int off = 32; off > 0; off >>= 1) v += __shfl_down(v, off, 64);
  return v;
}

// One block per batch. NO global atomics: each block stores 6 partials to its
// own slot part[b*8+k]; a 1-block reducer sums and finalizes.
__global__ __launch_bounds__(256) void k_batch(const float* __restrict__ x,
                                               const float* __restrict__ tg,
                                               float* __restrict__ part)
{
  const int b   = blockIdx.x;
  const int tid = threadIdx.x;

  __shared__ int   s_owner[CELLS];   // last-wins winning target tid, -1 = none
  __shared__ int   s_flags[CELLS];   // bits0..6 label set; bit15 = mask|ignore
  __shared__ float s_tx[Tn], s_ty[Tn], s_tw[Tn], s_th[Tn];

  for (int i = tid; i < CELLS; i += 256) { s_owner[i] = -1; s_flags[i] = 0; }
  __syncthreads();

  // ---- target phase: O(T) owner-map build, LDS atomics only ----
  if (tid < Tn) {
    const float* tp = tg + ((size_t)b * Tn + tid) * 5;
    float c0 = tp[0], c1 = tp[1], c2 = tp[2], c3 = tp[3], c4 = tp[4];
    bool valid = (c0 + c1 + c2 + c3 + c4) > 0.0f;
    float gx = c1 * (float)GWn, gy = c2 * (float)GHn;
    float gw = c3 * (float)GWn, gh = c4 * (float)GHn;
    float iou[NAn];
    int best = 0; float bestv = -1.0f;
#pragma unroll
    for (int a = 0; a < NAn; ++a) {
      float inter = fminf(gw, c_aw[a]) * fminf(gh, c_ah[a]);
      float u = inter / (gw * gh + c_aw[a] * c_ah[a] - inter + 1e-16f);
      iou[a] = u;
      if (u > bestv) { bestv = u; best = a; }     // first-max like argmax
    }
    int gi = (int)floorf(gx), gj = (int)floorf(gy);
    bool inb = (gi >= 0) && (gi < GWn) && (gj >= 0) && (gj < GHn); // mode='drop'
    s_tx[tid] = gx - floorf(gx);
    s_ty[tid] = gy - floorf(gy);
    s_tw[tid] = logf(gw / c_aw[best] + 1e-16f);
    s_th[tid] = logf(gh / c_ah[best] + 1e-16f);
    if (valid && inb) {
      int cell = best * (GHn * GWn) + gj * GWn + gi;
      atomicMax(&s_owner[cell], tid);             // last-wins = max tid
      int lbl = (int)c0;
      int lb  = (lbl >= 0 && lbl < NCn) ? (1 << lbl) : 0;  // mode='drop'
      atomicOr(&s_flags[cell], lb | EXCL);
#pragma unroll
      for (int a = 0; a < NAn; ++a) if (iou[a] > 0.6f)
        atomicOr(&s_flags[a * (GHn * GWn) + gj * GWn + gi], EXCL);
    }
  }
  __syncthreads();

  // ---- cell sweep: stream this batch's conf planes once, masked accumulate ----
  float v_mse = 0.f, v_pc = 0.f, v_cls = 0.f, v_neg = 0.f, v_np = 0.f, v_nc = 0.f;
  const float* xb = x + (size_t)b * (NAn * 14) * 512;

#pragma unroll
  for (int it = 0; it < CELLS / 256; ++it) {
    int cell = tid + it * 256;
    int a = cell >> 9, rest = cell & 511;
    const float* pl = xb + a * 14 * 512;
    float p6 = pl[6 * 512 + rest];                // coalesced conf stream
    int flags = s_flags[cell];
    if (!(flags & EXCL)) {                        // negative cell
      v_neg += negterm(p6);
      v_nc  += 1.0f;
    }
    int owner = s_owner[cell];
    if (owner >= 0) {                             // positive (masked) cell
      float p0 = pl[0 * 512 + rest];
      float p1 = pl[1 * 512 + rest];
      float p2 = pl[2 * 512 + rest];
      float p3 = pl[3 * 512 + rest];
      float dx = sigm(p0) - s_tx[owner];
      float dy = sigm(p1) - s_ty[owner];
      float dw = p2 - s_tw[owner];
      float dh = p3 - s_th[owner];
      v_mse += dx * dx + dy * dy + dw * dw + dh * dh;
      v_pc  += -logf(fmaxf(sigm(p6), 1e-12f));
      v_np  += 1.0f;
      int bits = flags & 0x7F;
      if (bits) {
        float s[NCn]; float m = -1e30f;
#pragma unroll
        for (int k = 0; k < NCn; ++k) {
          s[k] = sigm(pl[(size_t)(7 + k) * 512 + rest]);
          m = fmaxf(m, s[k]);
        }
        float ssum = 0.f;
#pragma unroll
        for (int k = 0; k < NCn; ++k) ssum += expf(s[k] - m);
        float lse = m + logf(ssum);
#pragma unroll
        for (int k = 0; k < NCn; ++k)
          if ((bits >> k) & 1) v_cls += lse - s[k];
      }
    }
  }

  // ---- block reduction, plain store to private slot ----
  __shared__ float red6[4][6];
  float vals[6] = {v_mse, v_pc, v_cls, v_neg, v_np, v_nc};
  int wid = tid >> 6, lane = tid & 63;
#pragma unroll
  for (int k = 0; k < 6; ++k) {
    float r = wred(vals[k]);
    if (lane == 0) red6[wid][k] = r;
  }
  __syncthreads();
  if (tid < 6)
    part[(size_t)b * 8 + tid] = red6[0][tid] + red6[1][tid] + red6[2][tid] + red6[3][tid];
}

__global__ __launch_bounds__(256) void k_red(const float* __restrict__ part,
                                             float* __restrict__ out)
{
  const int tid = threadIdx.x;
  float v[6] = {0.f, 0.f, 0.f, 0.f, 0.f, 0.f};
#pragma unroll
  for (int r = 0; r < 2; ++r) {
    const float* p = part + (size_t)(tid + r * 256) * 8;
#pragma unroll
    for (int k = 0; k < 6; ++k) v[k] += p[k];
  }
  __shared__ float red6[4][6];
  int wid = tid >> 6, lane = tid & 63;
#pragma unroll
  for (int k = 0; k < 6; ++k) {
    float r = wred(v[k]);
    if (lane == 0) red6[wid][k] = r;
  }
  __syncthreads();
  if (tid == 0) {
    float a0 = red6[0][0] + red6[1][0] + red6[2][0] + red6[3][0];
    float a1 = red6[0][1] + red6[1][1] + red6[2][1] + red6[3][1];
    float a2 = red6[0][2] + red6[1][2] + red6[2][2] + red6[3][2];
    float a3 = red6[0][3] + red6[1][3] + red6[2][3] + red6[3][3];
    float a4 = red6[0][4] + red6[1][4] + red6[2][4] + red6[3][4];
    float a5 = red6[0][5] + red6[1][5] + red6[2][5] + red6[3][5];
    float npos = fmaxf(a4, 1.0f);
    float negc = fmaxf(a5, 1.0f);
    out[0] = a0 / npos + a3 / negc + a1 / npos + a2 / ((float)Bn * npos);
  }
}

extern "C" void kernel_launch(void* const* d_in, const int* in_sizes, int n_in,
                              void* d_out, int out_size, void* d_ws, size_t ws_size,
                              hipStream_t stream)
{
  const float* x  = (const float*)d_in[0];
  const float* tg = (const float*)d_in[1];
  float* part = (float*)d_ws;                     // 512*8 floats = 16 KB

  k_batch<<<Bn, 256, 0, stream>>>(x, tg, part);
  k_red<<<1, 256, 0, stream>>>(part, (float*)d_out);
}